// Round 11
// baseline (338.415 us; speedup 1.0000x reference)
//
#include <hip/hip_runtime.h>
#include <stdint.h>

// Problem constants
#define BB   2
#define SS   2048
#define HID  2048
#define NHQ  16
#define NKV  8
#define DD   128
// QKV fused row layout: [q: 16*128 | k: 8*128 | v: 8*128] = 4096 bf16 per (b,s)
#define QKVW 4096

typedef __bf16 v8bf   __attribute__((ext_vector_type(8)));
typedef float  f32x4  __attribute__((ext_vector_type(4)));
typedef float  f32x16 __attribute__((ext_vector_type(16)));

__device__ __forceinline__ float bf2f(ushort u) {
    union { unsigned int i; float f; } x; x.i = ((unsigned int)u) << 16; return x.f;
}
__device__ __forceinline__ ushort f2bf(float f) {
    union { float f; unsigned int i; } x; x.f = f;
    unsigned int i = x.i;
    return (ushort)((i + 0x7fffu + ((i >> 16) & 1u)) >> 16); // RNE, finite inputs
}
__device__ __forceinline__ v8bf as_bf8(uint4 u) { return __builtin_bit_cast(v8bf, u); }

__device__ __forceinline__ unsigned int cvtpk_bf16(float lo, float hi) {
    unsigned int r;
    asm("v_cvt_pk_bf16_f32 %0, %1, %2" : "=v"(r) : "v"(lo), "v"(hi));
    return r;
}

__device__ __forceinline__ void store_el(float* p, float v)  { *p = v; }
__device__ __forceinline__ void store_el(ushort* p, float v) { *p = f2bf(v); }

// async global->LDS, 16B per lane; lds must be wave-uniform-base + lane*16
__device__ __forceinline__ void gll16(const ushort* g, ushort* l) {
    __builtin_amdgcn_global_load_lds(
        (const __attribute__((address_space(1))) void*)g,
        (__attribute__((address_space(3))) void*)l, 16, 0, 0);
}

// st_16x32 swizzle for [R][64] bf16 tiles (128B rows): byte ^= bit9<<5.
__device__ __forceinline__ int swz_off(int r, int lcolb) {
    return r * 64 + (((lcolb) ^ ((r & 4) << 3)) >> 1);
}
// same swizzle family for [R][32] bf16 tiles (64B rows): byte bit9 = (r>>3)&1.
__device__ __forceinline__ int hswz(int r, int colb) {
    return r * 32 + (((colb) ^ ((r & 8) << 2)) >> 1);
}

// ------------------------------------------------------------- fused prep kernel
// cast X, transpose-cast weights, and build the RoPE cos/sin table (2048x64 float2)
#define PREP_CAST   8192
#define PREP_WQ     (PREP_CAST)              // 64x64 tiles
#define PREP_WK     (PREP_WQ + 4096)         // 32x64
#define PREP_WV     (PREP_WK + 2048)
#define PREP_WO     (PREP_WV + 2048)         // 64x64
#define PREP_ROPE   (PREP_WO + 4096)
#define PREP_TOTAL  (PREP_ROPE + 512)        // 2048*64 entries / 256 thr

__device__ __forceinline__ void tcast_body(
    const float* __restrict__ in, ushort* __restrict__ out,
    int K, int N, int bx, int by, int t)
{
    __shared__ float tile[32][33];
    int n0 = bx * 32, k0 = by * 32;
    int tx = t & 31, ty = t >> 5; // 32 x 8
#pragma unroll
    for (int i = 0; i < 32; i += 8)
        tile[ty + i][tx] = in[(size_t)(k0 + ty + i) * N + n0 + tx];
    __syncthreads();
#pragma unroll
    for (int i = 0; i < 32; i += 8)
        out[(size_t)(n0 + ty + i) * K + k0 + tx] = f2bf(tile[tx][ty + i]);
}

__global__ __launch_bounds__(256) void prep(
    const float* __restrict__ X,  const float* __restrict__ wq,
    const float* __restrict__ wk, const float* __restrict__ wv,
    const float* __restrict__ wo,
    ushort* __restrict__ Xb, ushort* __restrict__ WqkvT, ushort* __restrict__ Wot,
    float2* __restrict__ rtab)
{
    int bid = blockIdx.x, t = threadIdx.x;
    if (bid < PREP_CAST) {
        int i = (bid * 256 + t) * 4;
        float4 v = *(const float4*)&X[i];
        ushort4 o = { f2bf(v.x), f2bf(v.y), f2bf(v.z), f2bf(v.w) };
        *(ushort4*)&Xb[i] = o;
    } else if (bid < PREP_WK) {
        int l = bid - PREP_WQ;
        tcast_body(wq, WqkvT, 2048, 2048, l & 63, l >> 6, t);
    } else if (bid < PREP_WV) {
        int l = bid - PREP_WK;
        tcast_body(wk, WqkvT + (size_t)2048 * 2048, 2048, 1024, l & 31, l >> 5, t);
    } else if (bid < PREP_WO) {
        int l = bid - PREP_WV;
        tcast_body(wv, WqkvT + (size_t)3072 * 2048, 2048, 1024, l & 31, l >> 5, t);
    } else if (bid < PREP_ROPE) {
        int l = bid - PREP_WO;
        tcast_body(wo, Wot, 2048, 2048, l & 63, l >> 6, t);
    } else {
        int e = (bid - PREP_ROPE) * 256 + t; // e = s*64 + d'
        int s = e >> 6, dp = e & 63;
        float inv = expf(-(float)dp * (1.0f / 64.0f) * 9.210340371976184f);
        float sn, cs;
        sincosf((float)s * inv, &sn, &cs);
        rtab[e] = make_float2(cs, sn);
    }
}

// ------------------------------------------- GEMM QKV: 256x256, BK=32, ring-2
// 2-phase double-buffered schedule, 8 waves (4M x 2N), per-wave output 64x128 =
// one head. LDS = 2 x (A 256x32 + B 256x32) x 2B = 64 KB -> 2 blocks/CU
// (16 waves/CU): two phase-offset blocks overlap each other's barrier/drain
// stalls (m114 mechanism, same as flash_attn). Stage depth 1: tile T+1's 4
// gll16 issue at tile T phase 0 into buf c^1 (last read at T-1, barrier-
// separated); end-of-tile vmcnt(0) waits on ~2500-cycle-old loads (near-free).
// Epilogue fuses per-head RMSNorm + RoPE (fp32, before bf16 cast).
__global__ __launch_bounds__(512, 2) void gemm_qkv(
    const ushort* __restrict__ A, const ushort* __restrict__ Bt,
    ushort* __restrict__ C, int M, int N, int K,
    const float* __restrict__ qnw, const float* __restrict__ knw,
    const float2* __restrict__ rtab)
{
    __shared__ __align__(16) ushort As[2][256 * 32];
    __shared__ __align__(16) ushort Bs[2][256 * 32];
    const int t = threadIdx.x;
    const int lane = t & 63, wave = t >> 6;
    const int quad = lane >> 4, l15 = lane & 15;
    const int m0 = blockIdx.y * 256, n0 = blockIdx.x * 256;
    const int wm = (wave >> 1) * 64;   // 4 M-waves
    const int wn = (wave & 1) * 128;   // 2 N-waves (one head each)

    const f32x4 zv = {0.f, 0.f, 0.f, 0.f};
    f32x4 acc[4][8];
#pragma unroll
    for (int i = 0; i < 4; i++)
#pragma unroll
        for (int j = 0; j < 8; j++) acc[i][j] = zv;

    int srow[2], scol[2];
#pragma unroll
    for (int j = 0; j < 2; j++) {
        int p16 = (j * 512 + t) * 16;
        int lg = p16 ^ (((p16 >> 9) & 1) << 5);
        srow[j] = lg >> 6; scol[j] = (lg & 63) >> 1;
    }
    int aoff[4], boff[8];
#pragma unroll
    for (int mf = 0; mf < 4; mf++) aoff[mf] = hswz(wm + mf * 16 + l15, quad * 16);
#pragma unroll
    for (int nf = 0; nf < 8; nf++) boff[nf] = hswz(wn + nf * 16 + l15, quad * 16);

#define STAGE_AQ(slot, kb)                                                           \
    {                                                                                \
        _Pragma("unroll")                                                            \
        for (int j = 0; j < 2; j++)                                                  \
            gll16(&A[(size_t)(m0 + srow[j]) * K + (kb) + scol[j]],                   \
                  &As[slot][(j * 512 + t) * 8]);                                     \
    }
#define STAGE_BQ(slot, kb)                                                           \
    {                                                                                \
        _Pragma("unroll")                                                            \
        for (int j = 0; j < 2; j++)                                                  \
            gll16(&Bt[(size_t)(n0 + srow[j]) * K + (kb) + scol[j]],                  \
                  &Bs[slot][(j * 512 + t) * 8]);                                     \
    }

    const int NT = K >> 5; // BK=32

    // prologue: stage tile 0, drain, barrier
    STAGE_AQ(0, 0); STAGE_BQ(0, 0);
    asm volatile("s_waitcnt vmcnt(0)" ::: "memory");
    __builtin_amdgcn_s_barrier();

    for (int T = 0; T < NT; T++) {
        const int c = T & 1;
        const ushort* Ac = &As[c][0];
        const ushort* Bc = &Bs[c][0];
        const int kn = (T + 1) << 5;
        const bool do_stage = (T + 1) < NT;

        // ---------- phase 0: read af + bf[0..3]; stage ALL of tile T+1; MFMA nf 0-3
        uint4 af[4], bf[4];
#pragma unroll
        for (int mf = 0; mf < 4; mf++) af[mf] = *(const uint4*)&Ac[aoff[mf]];
#pragma unroll
        for (int nf = 0; nf < 4; nf++) bf[nf] = *(const uint4*)&Bc[boff[nf]];
        if (do_stage) { STAGE_AQ(c ^ 1, kn); STAGE_BQ(c ^ 1, kn); }
        __builtin_amdgcn_s_barrier();
        asm volatile("s_waitcnt lgkmcnt(0)" ::: "memory");
        __builtin_amdgcn_sched_barrier(0);
        __builtin_amdgcn_s_setprio(1);
#pragma unroll
        for (int mf = 0; mf < 4; mf++)
#pragma unroll
            for (int nf = 0; nf < 4; nf++)
                acc[mf][nf] = __builtin_amdgcn_mfma_f32_16x16x32_bf16(
                    as_bf8(af[mf]), as_bf8(bf[nf]), acc[mf][nf], 0, 0, 0);
        __builtin_amdgcn_s_setprio(0);
        __builtin_amdgcn_s_barrier();

        // ---------- phase 1: read bf[4..7]; MFMA nf 4-7; drain T+1's stage
#pragma unroll
        for (int nf = 0; nf < 4; nf++) bf[nf] = *(const uint4*)&Bc[boff[4 + nf]];
        __builtin_amdgcn_s_barrier();
        asm volatile("s_waitcnt lgkmcnt(0)" ::: "memory");
        __builtin_amdgcn_sched_barrier(0);
        __builtin_amdgcn_s_setprio(1);
#pragma unroll
        for (int mf = 0; mf < 4; mf++)
#pragma unroll
            for (int nf = 0; nf < 4; nf++)
                acc[mf][4 + nf] = __builtin_amdgcn_mfma_f32_16x16x32_bf16(
                    as_bf8(af[mf]), as_bf8(bf[nf]), acc[mf][4 + nf], 0, 0, 0);
        __builtin_amdgcn_s_setprio(0);
        if (do_stage) asm volatile("s_waitcnt vmcnt(0)" ::: "memory"); // ~2500cy old
        __builtin_amdgcn_s_barrier();
    }
#undef STAGE_AQ
#undef STAGE_BQ

    // ---------------- epilogue: fused RMSNorm + RoPE for q/k cols, plain for v
    const int col0 = n0 + wn; // 128-aligned: this wave's head base column
    if (col0 >= 3072) {
#pragma unroll
        for (int mf = 0; mf < 4; mf++)
#pragma unroll
            for (int nf = 0; nf < 8; nf++)
#pragma unroll
                for (int r = 0; r < 4; r++) {
                    int row = m0 + wm + mf * 16 + quad * 4 + r;
                    C[(size_t)row * N + col0 + nf * 16 + l15] = f2bf(acc[mf][nf][r]);
                }
    } else {
        const bool isq = col0 < 2048;
        const float* nw = isq ? qnw : knw;
        // q scale = log2(e)/sqrt(128): scores land in log2 domain for flash's exp2
        const float scl = isq ? (0.08838834764831845f * 1.4426950408889634f) : 1.0f;
        float wgt[8];
#pragma unroll
        for (int nf = 0; nf < 8; nf++) wgt[nf] = nw[nf * 16 + l15];
#pragma unroll
        for (int mf = 0; mf < 4; mf++)
#pragma unroll
            for (int r = 0; r < 4; r++) {
                int row = m0 + wm + mf * 16 + quad * 4 + r;
                float v[8];
#pragma unroll
                for (int nf = 0; nf < 8; nf++) v[nf] = acc[mf][nf][r];
                float sum = 0.f;
#pragma unroll
                for (int nf = 0; nf < 8; nf++) sum = fmaf(v[nf], v[nf], sum);
#pragma unroll
                for (int xm = 1; xm < 16; xm <<= 1) sum += __shfl_xor(sum, xm, 64);
                float rr = rsqrtf(sum * (1.0f / 128.0f) + 1e-6f);
                int s = row & (SS - 1);
#pragma unroll
                for (int nf0 = 0; nf0 < 4; nf0++) {
                    float2 cs = rtab[s * 64 + nf0 * 16 + l15];
                    float x = v[nf0] * rr * wgt[nf0];
                    float y = v[nf0 + 4] * rr * wgt[nf0 + 4];
                    C[(size_t)row * N + col0 + nf0 * 16 + l15] =
                        f2bf((x * cs.x - y * cs.y) * scl);
                    C[(size_t)row * N + col0 + 64 + nf0 * 16 + l15] =
                        f2bf((y * cs.x + x * cs.y) * scl);
                }
            }
    }
}

// ---------------------------------------------------------------- GEMM: C = A @ Bt^T
// (out-projection) BM=256, BN=128, BK=64, 8 waves, ring-of-3 LDS (144 KB).
template <typename OutT>
__global__ __launch_bounds__(512, 2) void gemm_bt2(
    const ushort* __restrict__ A, const ushort* __restrict__ Bt,
    OutT* __restrict__ C, int M, int N, int K)
{
    __shared__ __align__(16) ushort As[3][256 * 64];
    __shared__ __align__(16) ushort Bs[3][128 * 64];
    const int t = threadIdx.x;
    const int lane = t & 63, wave = t >> 6;
    const int quad = lane >> 4, l15 = lane & 15;
    const int m0 = blockIdx.y * 256, n0 = blockIdx.x * 128;
    const int wm = (wave >> 1) * 64;
    const int wn = (wave & 1) * 64;

    const f32x4 zv = {0.f, 0.f, 0.f, 0.f};
    f32x4 acc[4][4];
#pragma unroll
    for (int i = 0; i < 4; i++)
#pragma unroll
        for (int j = 0; j < 4; j++) acc[i][j] = zv;

    int arow[4], acol[4];
#pragma unroll
    for (int j = 0; j < 4; j++) {
        int p = (j * 512 + t) * 16;
        int l = p ^ (((p >> 9) & 1) << 5);
        arow[j] = l >> 7; acol[j] = (l & 127) >> 1;
    }
    int brow[2], bcol[2];
#pragma unroll
    for (int j = 0; j < 2; j++) {
        int p = (j * 512 + t) * 16;
        int l = p ^ (((p >> 9) & 1) << 5);
        brow[j] = l >> 7; bcol[j] = (l & 127) >> 1;
    }

    int aoff[4][2], boff[2][2][2];
#pragma unroll
    for (int mf = 0; mf < 4; mf++)
#pragma unroll
        for (int kk = 0; kk < 2; kk++)
            aoff[mf][kk] = swz_off(wm + mf * 16 + l15, kk * 64 + quad * 16);
#pragma unroll
    for (int q = 0; q < 2; q++)
#pragma unroll
        for (int nf = 0; nf < 2; nf++)
#pragma unroll
            for (int kk = 0; kk < 2; kk++)
                boff[q][nf][kk] = swz_off(wn + q * 32 + nf * 16 + l15, kk * 64 + quad * 16);

#define STAGE_A(j, slot, kk0) \
    gll16(&A[(size_t)(m0 + arow[j]) * K + (kk0) + acol[j]], &As[slot][0] + ((j) * 512 + t) * 8)
#define STAGE_B(j, slot, kk0) \
    gll16(&Bt[(size_t)(n0 + brow[j]) * K + (kk0) + bcol[j]], &Bs[slot][0] + ((j) * 512 + t) * 8)

    const int NT = K >> 6;

#pragma unroll
    for (int j = 0; j < 4; j++) STAGE_A(j, 0, 0);
#pragma unroll
    for (int j = 0; j < 2; j++) STAGE_B(j, 0, 0);
#pragma unroll
    for (int j = 0; j < 4; j++) STAGE_A(j, 1, 64);
#pragma unroll
    for (int j = 0; j < 2; j++) STAGE_B(j, 1, 64);
    asm volatile("s_waitcnt vmcnt(6)" ::: "memory");
    __builtin_amdgcn_s_barrier();

    int cur = 0;
    for (int T = 0; T < NT; T++) {
        const ushort* Ac = &As[cur][0];
        const ushort* Bc = &Bs[cur][0];
        int stg = cur + 2; if (stg >= 3) stg -= 3;
        const int k2 = (T + 2) << 6;
        const bool do_stage = (T + 2) < NT;

        // ---------- phase 0
        uint4 af[4][2], bf[2][2];
#pragma unroll
        for (int mf = 0; mf < 4; mf++)
#pragma unroll
            for (int kk = 0; kk < 2; kk++)
                af[mf][kk] = *(const uint4*)&Ac[aoff[mf][kk]];
#pragma unroll
        for (int nf = 0; nf < 2; nf++)
#pragma unroll
            for (int kk = 0; kk < 2; kk++)
                bf[nf][kk] = *(const uint4*)&Bc[boff[0][nf][kk]];
        if (do_stage) {
            STAGE_A(0, stg, k2); STAGE_A(1, stg, k2); STAGE_B(0, stg, k2);
        }
        __builtin_amdgcn_s_barrier();
        asm volatile("s_waitcnt lgkmcnt(0)" ::: "memory");
        __builtin_amdgcn_sched_barrier(0);
        __builtin_amdgcn_s_setprio(1);
#pragma unroll
        for (int mf = 0; mf < 4; mf++)
#pragma unroll
            for (int nf = 0; nf < 2; nf++)
#pragma unroll
                for (int kk = 0; kk < 2; kk++)
                    acc[mf][nf] = __builtin_amdgcn_mfma_f32_16x16x32_bf16(
                        as_bf8(af[mf][kk]), as_bf8(bf[nf][kk]), acc[mf][nf], 0, 0, 0);
        __builtin_amdgcn_s_setprio(0);
        __builtin_amdgcn_s_barrier();

        // ---------- phase 1
#pragma unroll
        for (int nf = 0; nf < 2; nf++)
#pragma unroll
            for (int kk = 0; kk < 2; kk++)
                bf[nf][kk] = *(const uint4*)&Bc[boff[1][nf][kk]];
        if (do_stage) {
            STAGE_A(2, stg, k2); STAGE_A(3, stg, k2); STAGE_B(1, stg, k2);
            asm volatile("s_waitcnt vmcnt(6)" ::: "memory");
        } else if (T + 2 == NT) {
            asm volatile("s_waitcnt vmcnt(0)" ::: "memory");
        }
        __builtin_amdgcn_s_barrier();
        asm volatile("s_waitcnt lgkmcnt(0)" ::: "memory");
        __builtin_amdgcn_sched_barrier(0);
        __builtin_amdgcn_s_setprio(1);
#pragma unroll
        for (int mf = 0; mf < 4; mf++)
#pragma unroll
            for (int nf = 0; nf < 2; nf++)
#pragma unroll
                for (int kk = 0; kk < 2; kk++)
                    acc[mf][2 + nf] = __builtin_amdgcn_mfma_f32_16x16x32_bf16(
                        as_bf8(af[mf][kk]), as_bf8(bf[nf][kk]), acc[mf][2 + nf], 0, 0, 0);
        __builtin_amdgcn_s_setprio(0);
        __builtin_amdgcn_s_barrier();

        cur++; if (cur == 3) cur = 0;
    }
#undef STAGE_A
#undef STAGE_B

#pragma unroll
    for (int mf = 0; mf < 4; mf++)
#pragma unroll
        for (int nf = 0; nf < 4; nf++)
#pragma unroll
            for (int r = 0; r < 4; r++) {
                int row = m0 + wm + mf * 16 + quad * 4 + r;
                int col = n0 + wn + nf * 16 + l15;
                store_el(&C[(size_t)row * N + col], acc[mf][nf][r]);
            }
}

// ---------------------------------------------------------------- flash attention
// R3/R7 config (best measured, 5x verified ~94 us): 32 q/wave, 4 waves, q-tile
// 128, 2 blocks/CU. Swapped QK^T (T12) + double-buffered K via global_load_lds;
// V reg-prefetched; mid-tile barrier is lgkmcnt-only so vmem prefetches stay in
// flight. Madd in LDS (uniform-address reads broadcast -- free; R8 showed
// moving them to global-per-tile costs +10%). LDS: Ks 2x16K + Vt 16K + Madd 8K.
__global__ __launch_bounds__(256, 2) void flash_attn(
    const ushort* __restrict__ qkv, const float* __restrict__ mask, ushort* __restrict__ O)
{
    __shared__ __align__(16) ushort Ks[2][64 * 128]; // [key][dchunk ^ (key&15)]
    __shared__ __align__(16) ushort Vt[128 * 64];    // [d][keychunk ^ (d&7)]
    __shared__ __align__(16) float  Madd[SS];        // (1-mask)*-1e30 per key
    const int t = threadIdx.x;
    const int lane = t & 63, wave = t >> 6;
    const int l31 = lane & 31, half = lane >> 5;
    const int b = blockIdx.z, h = blockIdx.y, q0 = blockIdx.x * 128;
    const int kh = h >> 1; // GQA

#pragma unroll
    for (int i = 0; i < 2; i++) {
        int idx = i * 1024 + t * 4;
        float4 mv = *(const float4*)&mask[b * SS + idx];
        float4 o = { (1.f - mv.x) * -1e30f, (1.f - mv.y) * -1e30f,
                     (1.f - mv.z) * -1e30f, (1.f - mv.w) * -1e30f };
        *(float4*)&Madd[idx] = o;
    }

    uint4 aq[8];
    {
        const ushort* qp = qkv + ((size_t)(b * SS + q0 + wave * 32 + l31)) * QKVW + h * 128 + half * 8;
#pragma unroll
        for (int kt = 0; kt < 8; kt++) aq[kt] = *(const uint4*)&qp[kt * 16];
    }
    f32x16 acc_o[4];
#pragma unroll
    for (int i = 0; i < 4; i++)
#pragma unroll
        for (int r = 0; r < 16; r++) acc_o[i][r] = 0.f;
    float lp[4] = {0.f, 0.f, 0.f, 0.f};

    const ushort* Kg = qkv + (size_t)b * SS * QKVW + 2048 + kh * 128;
    const ushort* Vg = qkv + (size_t)b * SS * QKVW + 3072 + kh * 128;

    const int vp = t & 31, vdc = t >> 5;
    uint4 vreg[4];
#define LOAD_V(K0)                                                                  \
    {                                                                               \
        _Pragma("unroll")                                                           \
        for (int pass = 0; pass < 2; pass++) {                                      \
            int d0 = (vdc + pass * 8) * 8;                                          \
            vreg[pass * 2 + 0] = *(const uint4*)&Vg[(size_t)((K0) + 2 * vp) * QKVW + d0];     \
            vreg[pass * 2 + 1] = *(const uint4*)&Vg[(size_t)((K0) + 2 * vp + 1) * QKVW + d0]; \
        }                                                                           \
    }
#define STAGE_K(K0, buf)                                                            \
    {                                                                               \
        _Pragma("unroll")                                                           \
        for (int i = 0; i < 4; i++) {                                               \
            int chunk = i * 256 + t;                                                \
            int row = chunk >> 4, cp = chunk & 15;                                  \
            int cl = cp ^ (row & 15);                                               \
            gll16(&Kg[(size_t)((K0) + row) * QKVW + cl * 8], &Ks[buf][chunk * 8]);  \
        }                                                                           \
    }

    STAGE_K(0, 0);
    LOAD_V(0);

    for (int k0 = 0; k0 < SS; k0 += 64) {
        const int cur = (k0 >> 6) & 1;
        __syncthreads();
        if (k0 + 64 < SS) STAGE_K(k0 + 64, cur ^ 1);
#pragma unroll
        for (int pass = 0; pass < 2; pass++) {
            const ushort* pa_ = (const ushort*)&vreg[pass * 2 + 0];
            const ushort* pb_ = (const ushort*)&vreg[pass * 2 + 1];
            int d0 = (vdc + pass * 8) * 8;
#pragma unroll
            for (int j = 0; j < 8; j++) {
                int cp = (vp >> 2) ^ j;
                unsigned int v = (unsigned int)pa_[j] | ((unsigned int)pb_[j] << 16);
                *(unsigned int*)&Vt[(d0 + j) * 64 + cp * 8 + (vp & 3) * 2] = v;
            }
        }
        if (k0 + 64 < SS) LOAD_V(k0 + 64);
        asm volatile("s_waitcnt lgkmcnt(0)" ::: "memory");
        __builtin_amdgcn_sched_barrier(0);
        __builtin_amdgcn_s_barrier();

        f32x16 sc[2];
#pragma unroll
        for (int nt = 0; nt < 2; nt++)
#pragma unroll
            for (int g = 0; g < 4; g++) {
                f32x4 em = *(const f32x4*)&Madd[k0 + nt * 32 + 4 * half + g * 8];
#pragma unroll
                for (int j = 0; j < 4; j++) sc[nt][g * 4 + j] = em[j];
            }
        __builtin_amdgcn_s_setprio(1);
#pragma unroll
        for (int nt = 0; nt < 2; nt++) {
#pragma unroll
            for (int kt = 0; kt < 8; kt++) {
                int cp = (kt * 2 + half) ^ (l31 & 15);
                uint4 bk = *(const uint4*)&Ks[cur][(nt * 32 + l31) * 128 + cp * 8];
                sc[nt] = __builtin_amdgcn_mfma_f32_32x32x16_bf16(
                    as_bf8(bk), as_bf8(aq[kt]), sc[nt], 0, 0, 0);
            }
        }
        __builtin_amdgcn_s_setprio(0);

        uint4 pa[4];
#pragma unroll
        for (int nt = 0; nt < 2; nt++) {
            float p[16];
#pragma unroll
            for (int r = 0; r < 16; r++) {
                float pv = __builtin_amdgcn_exp2f(sc[nt][r]);
                p[r] = pv;
                lp[r & 3] += pv;
            }
            unsigned int pk[8];
#pragma unroll
            for (int i = 0; i < 8; i++) pk[i] = cvtpk_bf16(p[2 * i], p[2 * i + 1]);
            auto sA = __builtin_amdgcn_permlane32_swap(pk[0], pk[2], false, false);
            auto sB = __builtin_amdgcn_permlane32_swap(pk[1], pk[3], false, false);
            auto sC = __builtin_amdgcn_permlane32_swap(pk[4], pk[6], false, false);
            auto sD = __builtin_amdgcn_permlane32_swap(pk[5], pk[7], false, false);
            uint4 f0, f1;
            f0.x = sA[0]; f0.y = sB[0]; f0.z = sA[1]; f0.w = sB[1];
            f1.x = sC[0]; f1.y = sD[0]; f1.z = sC[1]; f1.w = sD[1];
            pa[nt * 2 + 0] = f0;
            pa[nt * 2 + 1] = f1;
        }

        __builtin_amdgcn_s_setprio(1);
#pragma unroll
        for (int kt2 = 0; kt2 < 4; kt2++) {
            int kc = kt2 * 2 + half;
            int co = (kc ^ (l31 & 7)) * 8;
#pragma unroll
            for (int nt = 0; nt < 4; nt++) {
                uint4 bv = *(const uint4*)&Vt[(nt * 32 + l31) * 64 + co];
                acc_o[nt] = __builtin_amdgcn_mfma_f32_32x32x16_bf16(
                    as_bf8(pa[kt2]), as_bf8(bv), acc_o[nt], 0, 0, 0);
            }
        }
        __builtin_amdgcn_s_setprio(0);
    }
    float lsum = (lp[0] + lp[1]) + (lp[2] + lp[3]);
    lsum += __shfl_xor(lsum, 32, 64);
    float linv = 1.0f / lsum;
    float li[16];
#pragma unroll
    for (int r = 0; r < 16; r++)
        li[r] = __shfl(linv, (r & 3) + 8 * (r >> 2) + 4 * half, 64);
#pragma unroll
    for (int nt = 0; nt < 4; nt++)
#pragma unroll
        for (int r = 0; r < 16; r++) {
            int prow = (r & 3) + 8 * (r >> 2) + 4 * half;
            int qrow = q0 + wave * 32 + prow;
            int d = nt * 32 + l31;
            float v = acc_o[nt][r] * li[r];
            O[((size_t)(b * SS + qrow)) * (NHQ * DD) + h * 128 + d] = f2bf(v);
        }
}

// ---------------------------------------------------------------- launch
extern "C" void kernel_launch(void* const* d_in, const int* in_sizes, int n_in,
                              void* d_out, int out_size, void* d_ws, size_t ws_size,
                              hipStream_t stream)
{
    const float* X    = (const float*)d_in[0];
    const float* mask = (const float*)d_in[1];
    const float* wq   = (const float*)d_in[2];
    const float* wk   = (const float*)d_in[3];
    const float* wv   = (const float*)d_in[4];
    const float* wo   = (const float*)d_in[5];
    const float* qnw  = (const float*)d_in[6];
    const float* knw  = (const float*)d_in[7];
    float* out = (float*)d_out;

    const size_t M = (size_t)BB * SS; // 4096
    ushort* Xb    = (ushort*)d_ws;                       // 4096x2048
    ushort* WqkvT = Xb    + M * HID;                     // 4096x2048 (Wq^T|Wk^T|Wv^T rows)
    ushort* Wot   = WqkvT + (size_t)4096 * HID;          // 2048x2048
    ushort* QKV   = Wot   + (size_t)2048 * 2048;         // 4096x4096
    ushort* Obuf  = QKV   + M * QKVW;                    // 4096x2048
    float2* rtab  = (float2*)(Obuf + M * (size_t)(NHQ * DD)); // 2048x64 cos/sin

    prep<<<PREP_TOTAL, 256, 0, stream>>>(X, wq, wk, wv, wo, Xb, WqkvT, Wot, rtab);

    // fused QKV projection + per-head RMSNorm + RoPE (epilogue-fused)
    gemm_qkv<<<dim3(4096 / 256, 4096 / 256), 512, 0, stream>>>(
        Xb, WqkvT, QKV, 4096, 4096, 2048, qnw, knw, rtab);

    flash_attn<<<dim3(SS / 128, NHQ, BB), 256, 0, stream>>>(QKV, mask, Obuf);

    // out projection: (4096,2048) @ (2048,2048)^T -> fp32 d_out
    gemm_bt2<float><<<dim3(2048 / 128, 4096 / 256), 512, 0, stream>>>(Obuf, Wot, out, 4096, 2048, 2048);
}

// Round 13
// 323.190 us; speedup vs baseline: 1.0471x; 1.0471x over previous
//
#include <hip/hip_runtime.h>
#include <stdint.h>

// Problem constants
#define BB   2
#define SS   2048
#define HID  2048
#define NHQ  16
#define NKV  8
#define DD   128
// QKV fused row layout: [q: 16*128 | k: 8*128 | v: 8*128] = 4096 bf16 per (b,s)
#define QKVW 4096

typedef __bf16 v8bf   __attribute__((ext_vector_type(8)));
typedef float  f32x4  __attribute__((ext_vector_type(4)));
typedef float  f32x16 __attribute__((ext_vector_type(16)));

__device__ __forceinline__ float bf2f(ushort u) {
    union { unsigned int i; float f; } x; x.i = ((unsigned int)u) << 16; return x.f;
}
__device__ __forceinline__ ushort f2bf(float f) {
    union { float f; unsigned int i; } x; x.f = f;
    unsigned int i = x.i;
    return (ushort)((i + 0x7fffu + ((i >> 16) & 1u)) >> 16); // RNE, finite inputs
}
__device__ __forceinline__ v8bf as_bf8(uint4 u) { return __builtin_bit_cast(v8bf, u); }

__device__ __forceinline__ unsigned int cvtpk_bf16(float lo, float hi) {
    unsigned int r;
    asm("v_cvt_pk_bf16_f32 %0, %1, %2" : "=v"(r) : "v"(lo), "v"(hi));
    return r;
}

__device__ __forceinline__ void store_el(float* p, float v)  { *p = v; }
__device__ __forceinline__ void store_el(ushort* p, float v) { *p = f2bf(v); }

// async global->LDS, 16B per lane; lds must be wave-uniform-base + lane*16
__device__ __forceinline__ void gll16(const ushort* g, ushort* l) {
    __builtin_amdgcn_global_load_lds(
        (const __attribute__((address_space(1))) void*)g,
        (__attribute__((address_space(3))) void*)l, 16, 0, 0);
}

// st_16x32 swizzle for [R][64] bf16 tiles (128B rows): byte ^= bit9<<5.
__device__ __forceinline__ int swz_off(int r, int lcolb) {
    return r * 64 + (((lcolb) ^ ((r & 4) << 3)) >> 1);
}
// same swizzle family for [R][32] bf16 tiles (64B rows): byte bit9 = (r>>3)&1.
__device__ __forceinline__ int hswz(int r, int colb) {
    return r * 32 + (((colb) ^ ((r & 8) << 2)) >> 1);
}

// ------------------------------------------------------------- fused prep kernel
// cast X, transpose-cast weights, and build the RoPE cos/sin table (2048x64 float2)
#define PREP_CAST   8192
#define PREP_WQ     (PREP_CAST)              // 64x64 tiles
#define PREP_WK     (PREP_WQ + 4096)         // 32x64
#define PREP_WV     (PREP_WK + 2048)
#define PREP_WO     (PREP_WV + 2048)         // 64x64
#define PREP_ROPE   (PREP_WO + 4096)
#define PREP_TOTAL  (PREP_ROPE + 512)        // 2048*64 entries / 256 thr

__device__ __forceinline__ void tcast_body(
    const float* __restrict__ in, ushort* __restrict__ out,
    int K, int N, int bx, int by, int t)
{
    __shared__ float tile[32][33];
    int n0 = bx * 32, k0 = by * 32;
    int tx = t & 31, ty = t >> 5; // 32 x 8
#pragma unroll
    for (int i = 0; i < 32; i += 8)
        tile[ty + i][tx] = in[(size_t)(k0 + ty + i) * N + n0 + tx];
    __syncthreads();
#pragma unroll
    for (int i = 0; i < 32; i += 8)
        out[(size_t)(n0 + ty + i) * K + k0 + tx] = f2bf(tile[tx][ty + i]);
}

__global__ __launch_bounds__(256) void prep(
    const float* __restrict__ X,  const float* __restrict__ wq,
    const float* __restrict__ wk, const float* __restrict__ wv,
    const float* __restrict__ wo,
    ushort* __restrict__ Xb, ushort* __restrict__ WqkvT, ushort* __restrict__ Wot,
    float2* __restrict__ rtab)
{
    int bid = blockIdx.x, t = threadIdx.x;
    if (bid < PREP_CAST) {
        int i = (bid * 256 + t) * 4;
        float4 v = *(const float4*)&X[i];
        ushort4 o = { f2bf(v.x), f2bf(v.y), f2bf(v.z), f2bf(v.w) };
        *(ushort4*)&Xb[i] = o;
    } else if (bid < PREP_WK) {
        int l = bid - PREP_WQ;
        tcast_body(wq, WqkvT, 2048, 2048, l & 63, l >> 6, t);
    } else if (bid < PREP_WV) {
        int l = bid - PREP_WK;
        tcast_body(wk, WqkvT + (size_t)2048 * 2048, 2048, 1024, l & 31, l >> 5, t);
    } else if (bid < PREP_WO) {
        int l = bid - PREP_WV;
        tcast_body(wv, WqkvT + (size_t)3072 * 2048, 2048, 1024, l & 31, l >> 5, t);
    } else if (bid < PREP_ROPE) {
        int l = bid - PREP_WO;
        tcast_body(wo, Wot, 2048, 2048, l & 63, l >> 6, t);
    } else {
        int e = (bid - PREP_ROPE) * 256 + t; // e = s*64 + d'
        int s = e >> 6, dp = e & 63;
        float inv = expf(-(float)dp * (1.0f / 64.0f) * 9.210340371976184f);
        float sn, cs;
        sincosf((float)s * inv, &sn, &cs);
        rtab[e] = make_float2(cs, sn);
    }
}

// ------------------------------------------- GEMM QKV: 256x256, BK=32, ring-3
// 2-phase ring-of-3 schedule, 8 waves (4M x 2N), per-wave output 64x128 = one
// head. LDS = 96 KB. vmcnt(4) counted once per tile (never 0 in the loop --
// R11 showed ring-2/vmcnt(0) costs +11 us). Epilogue fuses per-head RMSNorm +
// RoPE (fp32, before bf16 cast).
__global__ __launch_bounds__(512, 1) void gemm_qkv(
    const ushort* __restrict__ A, const ushort* __restrict__ Bt,
    ushort* __restrict__ C, int M, int N, int K,
    const float* __restrict__ qnw, const float* __restrict__ knw,
    const float2* __restrict__ rtab)
{
    __shared__ __align__(16) ushort As[3][256 * 32];
    __shared__ __align__(16) ushort Bs[3][256 * 32];
    const int t = threadIdx.x;
    const int lane = t & 63, wave = t >> 6;
    const int quad = lane >> 4, l15 = lane & 15;
    const int m0 = blockIdx.y * 256, n0 = blockIdx.x * 256;
    const int wm = (wave >> 1) * 64;   // 4 M-waves
    const int wn = (wave & 1) * 128;   // 2 N-waves (one head each)

    const f32x4 zv = {0.f, 0.f, 0.f, 0.f};
    f32x4 acc[4][8];
#pragma unroll
    for (int i = 0; i < 4; i++)
#pragma unroll
        for (int j = 0; j < 8; j++) acc[i][j] = zv;

    int srow[2], scol[2];
#pragma unroll
    for (int j = 0; j < 2; j++) {
        int p16 = (j * 512 + t) * 16;
        int lg = p16 ^ (((p16 >> 9) & 1) << 5);
        srow[j] = lg >> 6; scol[j] = (lg & 63) >> 1;
    }
    int aoff[4], boff[8];
#pragma unroll
    for (int mf = 0; mf < 4; mf++) aoff[mf] = hswz(wm + mf * 16 + l15, quad * 16);
#pragma unroll
    for (int nf = 0; nf < 8; nf++) boff[nf] = hswz(wn + nf * 16 + l15, quad * 16);

#define STAGE_AQ(slot, kb)                                                           \
    {                                                                                \
        _Pragma("unroll")                                                            \
        for (int j = 0; j < 2; j++)                                                  \
            gll16(&A[(size_t)(m0 + srow[j]) * K + (kb) + scol[j]],                   \
                  &As[slot][(j * 512 + t) * 8]);                                     \
    }
#define STAGE_BQ(slot, kb)                                                           \
    {                                                                                \
        _Pragma("unroll")                                                            \
        for (int j = 0; j < 2; j++)                                                  \
            gll16(&Bt[(size_t)(n0 + srow[j]) * K + (kb) + scol[j]],                  \
                  &Bs[slot][(j * 512 + t) * 8]);                                     \
    }

    const int NT = K >> 5; // BK=32

    STAGE_AQ(0, 0); STAGE_BQ(0, 0);
    STAGE_AQ(1, 32); STAGE_BQ(1, 32);
    asm volatile("s_waitcnt vmcnt(4)" ::: "memory");
    __builtin_amdgcn_s_barrier();

    int cur = 0;
    for (int T = 0; T < NT; T++) {
        const ushort* Ac = &As[cur][0];
        const ushort* Bc = &Bs[cur][0];
        int stg = cur + 2; if (stg >= 3) stg -= 3;
        const int k2 = (T + 2) << 5;
        const bool do_stage = (T + 2) < NT;

        // ---------- phase 0: read af + bf[0..3]; stage next A; MFMA nf 0-3
        uint4 af[4], bf[4];
#pragma unroll
        for (int mf = 0; mf < 4; mf++) af[mf] = *(const uint4*)&Ac[aoff[mf]];
#pragma unroll
        for (int nf = 0; nf < 4; nf++) bf[nf] = *(const uint4*)&Bc[boff[nf]];
        if (do_stage) STAGE_AQ(stg, k2);
        __builtin_amdgcn_s_barrier();
        asm volatile("s_waitcnt lgkmcnt(0)" ::: "memory");
        __builtin_amdgcn_sched_barrier(0);
        __builtin_amdgcn_s_setprio(1);
#pragma unroll
        for (int mf = 0; mf < 4; mf++)
#pragma unroll
            for (int nf = 0; nf < 4; nf++)
                acc[mf][nf] = __builtin_amdgcn_mfma_f32_16x16x32_bf16(
                    as_bf8(af[mf]), as_bf8(bf[nf]), acc[mf][nf], 0, 0, 0);
        __builtin_amdgcn_s_setprio(0);
        __builtin_amdgcn_s_barrier();

        // ---------- phase 1: read bf[4..7]; stage next B; counted vmcnt; MFMA nf 4-7
#pragma unroll
        for (int nf = 0; nf < 4; nf++) bf[nf] = *(const uint4*)&Bc[boff[4 + nf]];
        if (do_stage) {
            STAGE_BQ(stg, k2);
            asm volatile("s_waitcnt vmcnt(4)" ::: "memory"); // tile T+1 landed
        } else if (T + 2 == NT) {
            asm volatile("s_waitcnt vmcnt(0)" ::: "memory"); // epilogue drain
        }
        __builtin_amdgcn_s_barrier();
        asm volatile("s_waitcnt lgkmcnt(0)" ::: "memory");
        __builtin_amdgcn_sched_barrier(0);
        __builtin_amdgcn_s_setprio(1);
#pragma unroll
        for (int mf = 0; mf < 4; mf++)
#pragma unroll
            for (int nf = 0; nf < 4; nf++)
                acc[mf][4 + nf] = __builtin_amdgcn_mfma_f32_16x16x32_bf16(
                    as_bf8(af[mf]), as_bf8(bf[nf]), acc[mf][4 + nf], 0, 0, 0);
        __builtin_amdgcn_s_setprio(0);
        __builtin_amdgcn_s_barrier();

        cur++; if (cur == 3) cur = 0;
    }
#undef STAGE_AQ
#undef STAGE_BQ

    // ---------------- epilogue: fused RMSNorm + RoPE for q/k cols, plain for v
    const int col0 = n0 + wn; // 128-aligned: this wave's head base column
    if (col0 >= 3072) {
#pragma unroll
        for (int mf = 0; mf < 4; mf++)
#pragma unroll
            for (int nf = 0; nf < 8; nf++)
#pragma unroll
                for (int r = 0; r < 4; r++) {
                    int row = m0 + wm + mf * 16 + quad * 4 + r;
                    C[(size_t)row * N + col0 + nf * 16 + l15] = f2bf(acc[mf][nf][r]);
                }
    } else {
        const bool isq = col0 < 2048;
        const float* nw = isq ? qnw : knw;
        // q scale = log2(e)/sqrt(128): scores land in log2 domain for flash's exp2
        const float scl = isq ? (0.08838834764831845f * 1.4426950408889634f) : 1.0f;
        float wgt[8];
#pragma unroll
        for (int nf = 0; nf < 8; nf++) wgt[nf] = nw[nf * 16 + l15];
#pragma unroll
        for (int mf = 0; mf < 4; mf++)
#pragma unroll
            for (int r = 0; r < 4; r++) {
                int row = m0 + wm + mf * 16 + quad * 4 + r;
                float v[8];
#pragma unroll
                for (int nf = 0; nf < 8; nf++) v[nf] = acc[mf][nf][r];
                float sum = 0.f;
#pragma unroll
                for (int nf = 0; nf < 8; nf++) sum = fmaf(v[nf], v[nf], sum);
#pragma unroll
                for (int xm = 1; xm < 16; xm <<= 1) sum += __shfl_xor(sum, xm, 64);
                float rr = rsqrtf(sum * (1.0f / 128.0f) + 1e-6f);
                int s = row & (SS - 1);
#pragma unroll
                for (int nf0 = 0; nf0 < 4; nf0++) {
                    float2 cs = rtab[s * 64 + nf0 * 16 + l15];
                    float x = v[nf0] * rr * wgt[nf0];
                    float y = v[nf0 + 4] * rr * wgt[nf0 + 4];
                    C[(size_t)row * N + col0 + nf0 * 16 + l15] =
                        f2bf((x * cs.x - y * cs.y) * scl);
                    C[(size_t)row * N + col0 + 64 + nf0 * 16 + l15] =
                        f2bf((y * cs.x + x * cs.y) * scl);
                }
            }
    }
}

// ---------------------------------------------------------------- GEMM: C = A @ Bt^T
// (out-projection) BM=256, BN=128, BK=64, 8 waves, ring-of-3 LDS (144 KB).
template <typename OutT>
__global__ __launch_bounds__(512, 2) void gemm_bt2(
    const ushort* __restrict__ A, const ushort* __restrict__ Bt,
    OutT* __restrict__ C, int M, int N, int K)
{
    __shared__ __align__(16) ushort As[3][256 * 64];
    __shared__ __align__(16) ushort Bs[3][128 * 64];
    const int t = threadIdx.x;
    const int lane = t & 63, wave = t >> 6;
    const int quad = lane >> 4, l15 = lane & 15;
    const int m0 = blockIdx.y * 256, n0 = blockIdx.x * 128;
    const int wm = (wave >> 1) * 64;
    const int wn = (wave & 1) * 64;

    const f32x4 zv = {0.f, 0.f, 0.f, 0.f};
    f32x4 acc[4][4];
#pragma unroll
    for (int i = 0; i < 4; i++)
#pragma unroll
        for (int j = 0; j < 4; j++) acc[i][j] = zv;

    int arow[4], acol[4];
#pragma unroll
    for (int j = 0; j < 4; j++) {
        int p = (j * 512 + t) * 16;
        int l = p ^ (((p >> 9) & 1) << 5);
        arow[j] = l >> 7; acol[j] = (l & 127) >> 1;
    }
    int brow[2], bcol[2];
#pragma unroll
    for (int j = 0; j < 2; j++) {
        int p = (j * 512 + t) * 16;
        int l = p ^ (((p >> 9) & 1) << 5);
        brow[j] = l >> 7; bcol[j] = (l & 127) >> 1;
    }

    int aoff[4][2], boff[2][2][2];
#pragma unroll
    for (int mf = 0; mf < 4; mf++)
#pragma unroll
        for (int kk = 0; kk < 2; kk++)
            aoff[mf][kk] = swz_off(wm + mf * 16 + l15, kk * 64 + quad * 16);
#pragma unroll
    for (int q = 0; q < 2; q++)
#pragma unroll
        for (int nf = 0; nf < 2; nf++)
#pragma unroll
            for (int kk = 0; kk < 2; kk++)
                boff[q][nf][kk] = swz_off(wn + q * 32 + nf * 16 + l15, kk * 64 + quad * 16);

#define STAGE_A(j, slot, kk0) \
    gll16(&A[(size_t)(m0 + arow[j]) * K + (kk0) + acol[j]], &As[slot][0] + ((j) * 512 + t) * 8)
#define STAGE_B(j, slot, kk0) \
    gll16(&Bt[(size_t)(n0 + brow[j]) * K + (kk0) + bcol[j]], &Bs[slot][0] + ((j) * 512 + t) * 8)

    const int NT = K >> 6;

#pragma unroll
    for (int j = 0; j < 4; j++) STAGE_A(j, 0, 0);
#pragma unroll
    for (int j = 0; j < 2; j++) STAGE_B(j, 0, 0);
#pragma unroll
    for (int j = 0; j < 4; j++) STAGE_A(j, 1, 64);
#pragma unroll
    for (int j = 0; j < 2; j++) STAGE_B(j, 1, 64);
    asm volatile("s_waitcnt vmcnt(6)" ::: "memory");
    __builtin_amdgcn_s_barrier();

    int cur = 0;
    for (int T = 0; T < NT; T++) {
        const ushort* Ac = &As[cur][0];
        const ushort* Bc = &Bs[cur][0];
        int stg = cur + 2; if (stg >= 3) stg -= 3;
        const int k2 = (T + 2) << 6;
        const bool do_stage = (T + 2) < NT;

        // ---------- phase 0
        uint4 af[4][2], bf[2][2];
#pragma unroll
        for (int mf = 0; mf < 4; mf++)
#pragma unroll
            for (int kk = 0; kk < 2; kk++)
                af[mf][kk] = *(const uint4*)&Ac[aoff[mf][kk]];
#pragma unroll
        for (int nf = 0; nf < 2; nf++)
#pragma unroll
            for (int kk = 0; kk < 2; kk++)
                bf[nf][kk] = *(const uint4*)&Bc[boff[0][nf][kk]];
        if (do_stage) {
            STAGE_A(0, stg, k2); STAGE_A(1, stg, k2); STAGE_B(0, stg, k2);
        }
        __builtin_amdgcn_s_barrier();
        asm volatile("s_waitcnt lgkmcnt(0)" ::: "memory");
        __builtin_amdgcn_sched_barrier(0);
        __builtin_amdgcn_s_setprio(1);
#pragma unroll
        for (int mf = 0; mf < 4; mf++)
#pragma unroll
            for (int nf = 0; nf < 2; nf++)
#pragma unroll
                for (int kk = 0; kk < 2; kk++)
                    acc[mf][nf] = __builtin_amdgcn_mfma_f32_16x16x32_bf16(
                        as_bf8(af[mf][kk]), as_bf8(bf[nf][kk]), acc[mf][nf], 0, 0, 0);
        __builtin_amdgcn_s_setprio(0);
        __builtin_amdgcn_s_barrier();

        // ---------- phase 1
#pragma unroll
        for (int nf = 0; nf < 2; nf++)
#pragma unroll
            for (int kk = 0; kk < 2; kk++)
                bf[nf][kk] = *(const uint4*)&Bc[boff[1][nf][kk]];
        if (do_stage) {
            STAGE_A(2, stg, k2); STAGE_A(3, stg, k2); STAGE_B(1, stg, k2);
            asm volatile("s_waitcnt vmcnt(6)" ::: "memory");
        } else if (T + 2 == NT) {
            asm volatile("s_waitcnt vmcnt(0)" ::: "memory");
        }
        __builtin_amdgcn_s_barrier();
        asm volatile("s_waitcnt lgkmcnt(0)" ::: "memory");
        __builtin_amdgcn_sched_barrier(0);
        __builtin_amdgcn_s_setprio(1);
#pragma unroll
        for (int mf = 0; mf < 4; mf++)
#pragma unroll
            for (int nf = 0; nf < 2; nf++)
#pragma unroll
                for (int kk = 0; kk < 2; kk++)
                    acc[mf][2 + nf] = __builtin_amdgcn_mfma_f32_16x16x32_bf16(
                        as_bf8(af[mf][kk]), as_bf8(bf[nf][kk]), acc[mf][2 + nf], 0, 0, 0);
        __builtin_amdgcn_s_setprio(0);
        __builtin_amdgcn_s_barrier();

        cur++; if (cur == 3) cur = 0;
    }
#undef STAGE_A
#undef STAGE_B

#pragma unroll
    for (int mf = 0; mf < 4; mf++)
#pragma unroll
        for (int nf = 0; nf < 4; nf++)
#pragma unroll
            for (int r = 0; r < 4; r++) {
                int row = m0 + wm + mf * 16 + quad * 4 + r;
                int col = n0 + wn + nf * 16 + l15;
                store_el(&C[(size_t)row * N + col], acc[mf][nf][r]);
            }
}

// ---------------------------------------------------------------- flash attention
// Best measured (6x verified ~94 us): 32 q/wave, 4 waves, q-tile 128, 2
// blocks/CU. Swapped QK^T (T12) + double-buffered K via global_load_lds; V
// reg-prefetched; mid-tile barrier is lgkmcnt-only so vmem prefetches stay in
// flight. Madd in LDS (uniform-address reads broadcast -- free; R8 showed
// moving them to global-per-tile costs +10%). LDS: Ks 2x16K + Vt 16K + Madd 8K.
__global__ __launch_bounds__(256, 2) void flash_attn(
    const ushort* __restrict__ qkv, const float* __restrict__ mask, ushort* __restrict__ O)
{
    __shared__ __align__(16) ushort Ks[2][64 * 128]; // [key][dchunk ^ (key&15)]
    __shared__ __align__(16) ushort Vt[128 * 64];    // [d][keychunk ^ (d&7)]
    __shared__ __align__(16) float  Madd[SS];        // (1-mask)*-1e30 per key
    const int t = threadIdx.x;
    const int lane = t & 63, wave = t >> 6;
    const int l31 = lane & 31, half = lane >> 5;
    const int b = blockIdx.z, h = blockIdx.y, q0 = blockIdx.x * 128;
    const int kh = h >> 1; // GQA

#pragma unroll
    for (int i = 0; i < 2; i++) {
        int idx = i * 1024 + t * 4;
        float4 mv = *(const float4*)&mask[b * SS + idx];
        float4 o = { (1.f - mv.x) * -1e30f, (1.f - mv.y) * -1e30f,
                     (1.f - mv.z) * -1e30f, (1.f - mv.w) * -1e30f };
        *(float4*)&Madd[idx] = o;
    }

    uint4 aq[8];
    {
        const ushort* qp = qkv + ((size_t)(b * SS + q0 + wave * 32 + l31)) * QKVW + h * 128 + half * 8;
#pragma unroll
        for (int kt = 0; kt < 8; kt++) aq[kt] = *(const uint4*)&qp[kt * 16];
    }
    f32x16 acc_o[4];
#pragma unroll
    for (int i = 0; i < 4; i++)
#pragma unroll
        for (int r = 0; r < 16; r++) acc_o[i][r] = 0.f;
    float lp[4] = {0.f, 0.f, 0.f, 0.f};

    const ushort* Kg = qkv + (size_t)b * SS * QKVW + 2048 + kh * 128;
    const ushort* Vg = qkv + (size_t)b * SS * QKVW + 3072 + kh * 128;

    const int vp = t & 31, vdc = t >> 5;
    uint4 vreg[4];
#define LOAD_V(K0)                                                                  \
    {                                                                               \
        _Pragma("unroll")                                                           \
        for (int pass = 0; pass < 2; pass++) {                                      \
            int d0 = (vdc + pass * 8) * 8;                                          \
            vreg[pass * 2 + 0] = *(const uint4*)&Vg[(size_t)((K0) + 2 * vp) * QKVW + d0];     \
            vreg[pass * 2 + 1] = *(const uint4*)&Vg[(size_t)((K0) + 2 * vp + 1) * QKVW + d0]; \
        }                                                                           \
    }
#define STAGE_K(K0, buf)                                                            \
    {                                                                               \
        _Pragma("unroll")                                                           \
        for (int i = 0; i < 4; i++) {                                               \
            int chunk = i * 256 + t;                                                \
            int row = chunk >> 4, cp = chunk & 15;                                  \
            int cl = cp ^ (row & 15);                                               \
            gll16(&Kg[(size_t)((K0) + row) * QKVW + cl * 8], &Ks[buf][chunk * 8]);  \
        }                                                                           \
    }

    STAGE_K(0, 0);
    LOAD_V(0);

    for (int k0 = 0; k0 < SS; k0 += 64) {
        const int cur = (k0 >> 6) & 1;
        __syncthreads();
        if (k0 + 64 < SS) STAGE_K(k0 + 64, cur ^ 1);
#pragma unroll
        for (int pass = 0; pass < 2; pass++) {
            const ushort* pa_ = (const ushort*)&vreg[pass * 2 + 0];
            const ushort* pb_ = (const ushort*)&vreg[pass * 2 + 1];
            int d0 = (vdc + pass * 8) * 8;
#pragma unroll
            for (int j = 0; j < 8; j++) {
                int cp = (vp >> 2) ^ j;
                unsigned int v = (unsigned int)pa_[j] | ((unsigned int)pb_[j] << 16);
                *(unsigned int*)&Vt[(d0 + j) * 64 + cp * 8 + (vp & 3) * 2] = v;
            }
        }
        if (k0 + 64 < SS) LOAD_V(k0 + 64);
        asm volatile("s_waitcnt lgkmcnt(0)" ::: "memory");
        __builtin_amdgcn_sched_barrier(0);
        __builtin_amdgcn_s_barrier();

        f32x16 sc[2];
#pragma unroll
        for (int nt = 0; nt < 2; nt++)
#pragma unroll
            for (int g = 0; g < 4; g++) {
                f32x4 em = *(const f32x4*)&Madd[k0 + nt * 32 + 4 * half + g * 8];
#pragma unroll
                for (int j = 0; j < 4; j++) sc[nt][g * 4 + j] = em[j];
            }
        __builtin_amdgcn_s_setprio(1);
#pragma unroll
        for (int nt = 0; nt < 2; nt++) {
#pragma unroll
            for (int kt = 0; kt < 8; kt++) {
                int cp = (kt * 2 + half) ^ (l31 & 15);
                uint4 bk = *(const uint4*)&Ks[cur][(nt * 32 + l31) * 128 + cp * 8];
                sc[nt] = __builtin_amdgcn_mfma_f32_32x32x16_bf16(
                    as_bf8(bk), as_bf8(aq[kt]), sc[nt], 0, 0, 0);
            }
        }
        __builtin_amdgcn_s_setprio(0);

        uint4 pa[4];
#pragma unroll
        for (int nt = 0; nt < 2; nt++) {
            float p[16];
#pragma unroll
            for (int r = 0; r < 16; r++) {
                float pv = __builtin_amdgcn_exp2f(sc[nt][r]);
                p[r] = pv;
                lp[r & 3] += pv;
            }
            unsigned int pk[8];
#pragma unroll
            for (int i = 0; i < 8; i++) pk[i] = cvtpk_bf16(p[2 * i], p[2 * i + 1]);
            auto sA = __builtin_amdgcn_permlane32_swap(pk[0], pk[2], false, false);
            auto sB = __builtin_amdgcn_permlane32_swap(pk[1], pk[3], false, false);
            auto sC = __builtin_amdgcn_permlane32_swap(pk[4], pk[6], false, false);
            auto sD = __builtin_amdgcn_permlane32_swap(pk[5], pk[7], false, false);
            uint4 f0, f1;
            f0.x = sA[0]; f0.y = sB[0]; f0.z = sA[1]; f0.w = sB[1];
            f1.x = sC[0]; f1.y = sD[0]; f1.z = sC[1]; f1.w = sD[1];
            pa[nt * 2 + 0] = f0;
            pa[nt * 2 + 1] = f1;
        }

        __builtin_amdgcn_s_setprio(1);
#pragma unroll
        for (int kt2 = 0; kt2 < 4; kt2++) {
            int kc = kt2 * 2 + half;
            int co = (kc ^ (l31 & 7)) * 8;
#pragma unroll
            for (int nt = 0; nt < 4; nt++) {
                uint4 bv = *(const uint4*)&Vt[(nt * 32 + l31) * 64 + co];
                acc_o[nt] = __builtin_amdgcn_mfma_f32_32x32x16_bf16(
                    as_bf8(pa[kt2]), as_bf8(bv), acc_o[nt], 0, 0, 0);
            }
        }
        __builtin_amdgcn_s_setprio(0);
    }
    float lsum = (lp[0] + lp[1]) + (lp[2] + lp[3]);
    lsum += __shfl_xor(lsum, 32, 64);
    float linv = 1.0f / lsum;
    float li[16];
#pragma unroll
    for (int r = 0; r < 16; r++)
        li[r] = __shfl(linv, (r & 3) + 8 * (r >> 2) + 4 * half, 64);
#pragma unroll
    for (int nt = 0; nt < 4; nt++)
#pragma unroll
        for (int r = 0; r < 16; r++) {
            int prow = (r & 3) + 8 * (r >> 2) + 4 * half;
            int qrow = q0 + wave * 32 + prow;
            int d = nt * 32 + l31;
            float v = acc_o[nt][r] * li[r];
            O[((size_t)(b * SS + qrow)) * (NHQ * DD) + h * 128 + d] = f2bf(v);
        }
}

// ---------------------------------------------------------------- launch
extern "C" void kernel_launch(void* const* d_in, const int* in_sizes, int n_in,
                              void* d_out, int out_size, void* d_ws, size_t ws_size,
                              hipStream_t stream)
{
    const float* X    = (const float*)d_in[0];
    const float* mask = (const float*)d_in[1];
    const float* wq   = (const float*)d_in[2];
    const float* wk   = (const float*)d_in[3];
    const float* wv   = (const float*)d_in[4];
    const float* wo   = (const float*)d_in[5];
    const float* qnw  = (const float*)d_in[6];
    const float* knw  = (const float*)d_in[7];
    float* out = (float*)d_out;

    const size_t M = (size_t)BB * SS; // 4096
    ushort* Xb    = (ushort*)d_ws;                       // 4096x2048
    ushort* WqkvT = Xb    + M * HID;                     // 4096x2048 (Wq^T|Wk^T|Wv^T rows)
    ushort* Wot   = WqkvT + (size_t)4096 * HID;          // 2048x2048
    ushort* QKV   = Wot   + (size_t)2048 * 2048;         // 4096x4096
    ushort* Obuf  = QKV   + M * QKVW;                    // 4096x2048
    float2* rtab  = (float2*)(Obuf + M * (size_t)(NHQ * DD)); // 2048x64 cos/sin

    prep<<<PREP_TOTAL, 256, 0, stream>>>(X, wq, wk, wv, wo, Xb, WqkvT, Wot, rtab);

    // fused QKV projection + per-head RMSNorm + RoPE (epilogue-fused)
    gemm_qkv<<<dim3(4096 / 256, 4096 / 256), 512, 0, stream>>>(
        Xb, WqkvT, QKV, 4096, 4096, 2048, qnw, knw, rtab);

    flash_attn<<<dim3(SS / 128, NHQ, BB), 256, 0, stream>>>(QKV, mask, Obuf);

    // out projection: (4096,2048) @ (2048,2048)^T -> fp32 d_out
    gemm_bt2<float><<<dim3(2048 / 128, 4096 / 256), 512, 0, stream>>>(Obuf, Wot, out, 4096, 2048, 2048);
}